// Round 1
// baseline (88.412 us; speedup 1.0000x reference)
//
#include <hip/hip_runtime.h>
#include <math.h>

#define FIN 128
#define FOUT 128
#define RB 64            // rows per block
#define LSTR 129         // LDS row stride (pad +1: conflict-free lane-n reads)

__global__ __launch_bounds__(256) void kan_fwd(
    const float* __restrict__ x,
    const float* __restrict__ bw,
    const float* __restrict__ sw,
    float* __restrict__ out)
{
    __shared__ float s_u[RB * LSTR];
    __shared__ float s_s[RB * LSTR];

    const int tid = threadIdx.x;
    const int nl  = tid & 63;           // lane = row within block
    const int ohg = tid >> 6;           // 0..3
    const int rb  = blockIdx.y;         // 0..31
    const int ob  = blockIdx.x;         // 0..7
    const int n0  = rb * RB;

    const float G0 = -2.2f;             // GRID_MIN - 3*H
    const float Hh = 0.4f;

    // ---- staging: silu + u for 64 rows x 128 feats (coalesced reads) ----
    for (int e = tid; e < RB * FIN; e += 256) {
        int r = e >> 7;
        int i = e & 127;
        float xv = x[(n0 + r) * FIN + i];
        float si = xv / (1.0f + expf(-xv));
        float xn = fminf(fmaxf(xv, -1.0f), 1.0f);
        float t  = (xn - G0) / Hh;       // true division, matches XLA
        float u  = t - floorf(t);        // UNclipped floor, per reference
        s_u[r * LSTR + i] = u;
        s_s[r * LSTR + i] = si;
    }

    // oh is wave-uniform by construction; make it provably so for s_loads
    const int oh = __builtin_amdgcn_readfirstlane(ob * 4 + ohg);  // 0..31
    const int n  = n0 + nl;

    // ---- per-thread gather offsets: c depends on x[n, m], m = oh + 32b ----
    int off0, off1, off2, off3;
    {
        int offs[4];
#pragma unroll
        for (int b = 0; b < 4; ++b) {
            int m = oh + 32 * b;
            float xv = x[n * FIN + m];
            float xn = fminf(fmaxf(xv, -1.0f), 1.0f);
            float t  = (xn - G0) / Hh;
            int idx  = (int)floorf(t);
            idx = min(max(idx, 3), 7);
            offs[b] = m * 8 + (idx - 3);   // dword offset within a-slice
        }
        off0 = offs[0]; off1 = offs[1]; off2 = offs[2]; off3 = offs[3];
    }

    __syncthreads();

    const float* bw0 = bw + (oh * 4 + 0) * FIN;   // uniform rows -> s_loads
    const float* bw1 = bw + (oh * 4 + 1) * FIN;
    const float* bw2 = bw + (oh * 4 + 2) * FIN;
    const float* bw3 = bw + (oh * 4 + 3) * FIN;

    float acc0 = 0.f, acc1 = 0.f, acc2 = 0.f, acc3 = 0.f;

#pragma unroll 2
    for (int a = 0; a < FIN; ++a) {
        float u  = s_u[nl * LSTR + a];
        float si = s_s[nl * LSTR + a];
        float u2 = u * u;
        float u3 = u2 * u;
        float om = 1.0f - u;
        float b0 = om * om * om * (1.0f / 6.0f);
        float b1 = 0.5f * u3 - u2 + (2.0f / 3.0f);
        float b2 = -0.5f * u3 + 0.5f * u2 + 0.5f * u + (1.0f / 6.0f);
        float b3 = u3 * (1.0f / 6.0f);

        const float* sa = sw + a * 1024;
        const float* p0 = sa + off0;
        const float* p1 = sa + off1;
        const float* p2 = sa + off2;
        const float* p3 = sa + off3;

        // spline: acc[ol] += b_b * SW[a*1024 + m_b*8 + c_b + ol]
        acc0 += b0 * p0[0]; acc1 += b0 * p0[1]; acc2 += b0 * p0[2]; acc3 += b0 * p0[3];
        acc0 += b1 * p1[0]; acc1 += b1 * p1[1]; acc2 += b1 * p1[2]; acc3 += b1 * p1[3];
        acc0 += b2 * p2[0]; acc1 += b2 * p2[1]; acc2 += b2 * p2[2]; acc3 += b2 * p2[3];
        acc0 += b3 * p3[0]; acc1 += b3 * p3[1]; acc2 += b3 * p3[2]; acc3 += b3 * p3[3];

        // base: silu(x) @ bw.T   (bw loads are wave-uniform -> scalar)
        acc0 += si * bw0[a];
        acc1 += si * bw1[a];
        acc2 += si * bw2[a];
        acc3 += si * bw3[a];
    }

    float4 o4;
    o4.x = acc0; o4.y = acc1; o4.z = acc2; o4.w = acc3;
    *(float4*)(out + n * FOUT + oh * 4) = o4;
}

extern "C" void kernel_launch(void* const* d_in, const int* in_sizes, int n_in,
                              void* d_out, int out_size, void* d_ws, size_t ws_size,
                              hipStream_t stream) {
    const float* x  = (const float*)d_in[0];
    const float* bw = (const float*)d_in[1];
    const float* sw = (const float*)d_in[2];
    float* out = (float*)d_out;
    dim3 grid(8, 32);   // 8 o-blocks x 32 row-blocks
    kan_fwd<<<grid, dim3(256), 0, stream>>>(x, bw, sw, out);
}

// Round 2
// 76.314 us; speedup vs baseline: 1.1585x; 1.1585x over previous
//
#include <hip/hip_runtime.h>
#include <math.h>

#define FIN 128
#define FOUT 128
#define RB 64            // rows per block
#define LSTR 129         // LDS row stride for float arrays (pad +1)
#define CSTR 132         // LDS row stride for c-bytes (33 dwords -> conflict-free)

// Block: 1024 threads = 16 waves = 4 oh-groups x 4 K-splits.
// Grid: 8 o-blocks x 32 row-blocks = 256 blocks -> 16 waves/CU, 4 waves/SIMD.
__global__ __launch_bounds__(1024) void kan_fwd(
    const float* __restrict__ x,
    const float* __restrict__ bw,
    const float* __restrict__ sw,
    float* __restrict__ out)
{
    __shared__ float smem[2 * RB * LSTR];        // s_u | s_s; reused as reduce buf
    __shared__ unsigned char s_c[RB * CSTR];     // clipped floor index per (row, feat)
    float* s_u = smem;
    float* s_s = smem + RB * LSTR;

    const int tid = threadIdx.x;
    const int nl  = tid & 63;                    // lane = row within block
    const int w   = __builtin_amdgcn_readfirstlane(tid >> 6);  // wave id 0..15
    const int ohg = w & 3;                       // oh sub-group 0..3
    const int ks  = w >> 2;                      // K-split 0..3
    const int rb  = blockIdx.y;                  // 0..31
    const int ob  = blockIdx.x;                  // 0..7
    const int n0  = rb * RB;

    const float G0 = -2.2f;                      // GRID_MIN - 3*H
    const float Hh = 0.4f;

    // ---- staging: silu, u, and clipped floor idx for 64 rows x 128 feats ----
    for (int e = tid; e < RB * FIN; e += 1024) {
        int r = e >> 7;
        int i = e & 127;
        float xv = x[(n0 + r) * FIN + i];
        float si = xv / (1.0f + expf(-xv));
        float xn = fminf(fmaxf(xv, -1.0f), 1.0f);
        float t  = (xn - G0) / Hh;               // true division, matches XLA
        float u  = t - floorf(t);                // UNclipped floor, per reference
        int idx  = (int)floorf(t);
        idx = min(max(idx, 3), 7);
        s_u[r * LSTR + i] = u;
        s_s[r * LSTR + i] = si;
        s_c[r * CSTR + i] = (unsigned char)(idx - 3);
    }

    const int oh = __builtin_amdgcn_readfirstlane(ob * 4 + ohg);  // 0..31
    const int n  = n0 + nl;

    __syncthreads();

    // ---- per-thread gather offsets from LDS (c depends on x[n, m], m = oh+32b) ----
    int off0 = (oh +  0) * 8 + s_c[nl * CSTR + oh +  0];
    int off1 = (oh + 32) * 8 + s_c[nl * CSTR + oh + 32];
    int off2 = (oh + 64) * 8 + s_c[nl * CSTR + oh + 64];
    int off3 = (oh + 96) * 8 + s_c[nl * CSTR + oh + 96];

    const float* bw0 = bw + (oh * 4 + 0) * FIN;  // uniform rows -> s_loads
    const float* bw1 = bw + (oh * 4 + 1) * FIN;
    const float* bw2 = bw + (oh * 4 + 2) * FIN;
    const float* bw3 = bw + (oh * 4 + 3) * FIN;

    float acc0 = 0.f, acc1 = 0.f, acc2 = 0.f, acc3 = 0.f;

    const int a0 = ks * 32;
#pragma unroll 4
    for (int j = 0; j < 32; ++j) {
        const int a = a0 + j;
        float u  = s_u[nl * LSTR + a];
        float si = s_s[nl * LSTR + a];
        float u2 = u * u;
        float u3 = u2 * u;
        float om = 1.0f - u;
        float b0 = om * om * om * (1.0f / 6.0f);
        float b1 = 0.5f * u3 - u2 + (2.0f / 3.0f);
        float b2 = -0.5f * u3 + 0.5f * u2 + 0.5f * u + (1.0f / 6.0f);
        float b3 = u3 * (1.0f / 6.0f);

        const float* sa = sw + a * 1024;
        const float* p0 = sa + off0;
        const float* p1 = sa + off1;
        const float* p2 = sa + off2;
        const float* p3 = sa + off3;

        acc0 += b0 * p0[0]; acc1 += b0 * p0[1]; acc2 += b0 * p0[2]; acc3 += b0 * p0[3];
        acc0 += b1 * p1[0]; acc1 += b1 * p1[1]; acc2 += b1 * p1[2]; acc3 += b1 * p1[3];
        acc0 += b2 * p2[0]; acc1 += b2 * p2[1]; acc2 += b2 * p2[2]; acc3 += b2 * p2[3];
        acc0 += b3 * p3[0]; acc1 += b3 * p3[1]; acc2 += b3 * p3[2]; acc3 += b3 * p3[3];

        acc0 += si * bw0[a];
        acc1 += si * bw1[a];
        acc2 += si * bw2[a];
        acc3 += si * bw3[a];
    }

    // ---- cross-split reduction via LDS (alias smem; s_u/s_s dead now) ----
    __syncthreads();                              // all reads of s_u/s_s done
    float* red = smem;                            // 1024 threads x 4 floats = 16 KB
    ((float4*)red)[tid] = make_float4(acc0, acc1, acc2, acc3);
    __syncthreads();

    if (tid < 256) {
        int ohg2  = tid >> 6;
        int lane2 = tid & 63;
        float4 r0 = ((float4*)red)[0 * 256 + tid];
        float4 r1 = ((float4*)red)[1 * 256 + tid];
        float4 r2 = ((float4*)red)[2 * 256 + tid];
        float4 r3 = ((float4*)red)[3 * 256 + tid];
        float4 o4;
        o4.x = r0.x + r1.x + r2.x + r3.x;
        o4.y = r0.y + r1.y + r2.y + r3.y;
        o4.z = r0.z + r1.z + r2.z + r3.z;
        o4.w = r0.w + r1.w + r2.w + r3.w;
        *(float4*)(out + (n0 + lane2) * FOUT + (ob * 4 + ohg2) * 4) = o4;
    }
}

extern "C" void kernel_launch(void* const* d_in, const int* in_sizes, int n_in,
                              void* d_out, int out_size, void* d_ws, size_t ws_size,
                              hipStream_t stream) {
    const float* x  = (const float*)d_in[0];
    const float* bw = (const float*)d_in[1];
    const float* sw = (const float*)d_in[2];
    float* out = (float*)d_out;
    dim3 grid(8, 32);   // 8 o-blocks x 32 row-blocks
    kan_fwd<<<grid, dim3(1024), 0, stream>>>(x, bw, sw, out);
}